// Round 14
// baseline (24.228 us; speedup 1.0000x reference)
//
#include <hip/hip_runtime.h>
#include <hip/hip_fp16.h>
#include <math.h>

// Problem constants (match reference)
#define Bb   16
#define Cc   3
#define Hh   64
#define Ww   64
#define Kk   32
#define Ss   32
#define OHh  60
#define OWw  60
#define Pp   3600
#define STRIP 12           // output rows per block
#define NSTRIP 5           // 5 strips of 12 = 60 rows
#define SROWS 16           // staged rows: 12 + R-1
#define NGRP 180           // 12 rows * 15 groups of 4 cols
#define TPB  192           // 3 waves; >= NGRP, 94% lane util

// fp16 LDS layout (dword units): row = 33 dwords. Bank stride/row = 1 ->
// oh-major lanes conflict-free. Two copies (shift 0/1 col): every 4-px
// gather is one ds_read2_b32, dwords are direct __half2 operands.
#define DWROW  33
#define DWC    (SROWS * DWROW)  // 528 dwords per channel
#define DWCOPY (Cc * DWC)       // 1584 dwords per copy

typedef float vf4 __attribute__((ext_vector_type(4)));
typedef float vf4u __attribute__((ext_vector_type(4), aligned(4)));

#define SB __builtin_amdgcn_sched_barrier(0)

static __device__ __forceinline__ unsigned int pkh(float lo, float hi) {
    __half2 h = __floats2half2_rn(lo, hi);
    return *reinterpret_cast<unsigned int*>(&h);
}
static __device__ __forceinline__ __half2 bc(unsigned int u) {
    return *reinterpret_cast<__half2*>(&u);
}
static __device__ __forceinline__ unsigned int bits(__half2 h) {
    return *reinterpret_cast<unsigned int*>(&h);
}

// fp16 combine on 4 px (2 half2): y = c0 + a*dA + b*dB + a*b*dAB
// coef uint4 = pre-broadcast half2: {c0,c0},{dA,dA},{dB,dB},{dAB,dAB}
static __device__ __forceinline__ uint2 comb2(uint2 a, uint2 b, uint4 c) {
    const __half2 cc0 = bc(c.x), ccA = bc(c.y), ccB = bc(c.z), ccAB = bc(c.w);
    const __half2 tx = __hfma2(bc(b.x), ccAB, ccA);
    const __half2 ty = __hfma2(bc(b.y), ccAB, ccA);
    const __half2 ux = __hfma2(bc(b.x), ccB, cc0);
    const __half2 uy = __hfma2(bc(b.y), ccB, cc0);
    uint2 r;
    r.x = bits(__hfma2(bc(a.x), tx, ux));
    r.y = bits(__hfma2(bc(a.y), ty, uy));
    return r;
}

// raw gather: two adjacent dwords -> one ds_read2_b32 (base is SGPR-resident)
#define GR(sb, dst) { dst.x = xsh[(sb) + loff]; dst.y = xsh[(sb) + loff + 1]; }

// prologue: wave-uniform leaf bases -> SGPRs (readfirstlane)
#define RFL(S, J, IDX)                                                        \
    const int sbx##S##_##J = __builtin_amdgcn_readfirstlane(bases[(IDX)].x);  \
    const int sby##S##_##J = __builtin_amdgcn_readfirstlane(bases[(IDX)].y);

// issue stage-S gathers (8 ds_read2_b32)
#define PREG(S)                                                               \
    uint2 ga##S##_0, gb##S##_0, ga##S##_1, gb##S##_1;                         \
    uint2 ga##S##_2, gb##S##_2, ga##S##_3, gb##S##_3;                         \
    GR(sbx##S##_0, ga##S##_0); GR(sby##S##_0, gb##S##_0);                     \
    GR(sbx##S##_1, ga##S##_1); GR(sby##S##_1, gb##S##_1);                     \
    GR(sbx##S##_2, ga##S##_2); GR(sby##S##_2, gb##S##_2);                     \
    GR(sbx##S##_3, ga##S##_3); GR(sby##S##_3, gb##S##_3);

// read stage-S coefficients (7 uniform b128, LDS broadcast)
#define COEF(S)                                                               \
    const uint4 kc##S##_0 = coefb[4*(S)],    kc##S##_1 = coefb[4*(S)+1];      \
    const uint4 kc##S##_2 = coefb[4*(S)+2],  kc##S##_3 = coefb[4*(S)+3];      \
    const uint4 kd##S##_0 = coefb[32+2*(S)], kd##S##_1 = coefb[33+2*(S)];     \
    const uint4 ke##S = coefb[48+(S)];

// fp16 FMA tree for stage S
#define FMAS(S, FOLD)                                                         \
    uint2 t4_##S;                                                             \
    {                                                                         \
        const uint2 u0 = comb2(ga##S##_0, gb##S##_0, kc##S##_0);              \
        const uint2 u1 = comb2(ga##S##_1, gb##S##_1, kc##S##_1);              \
        const uint2 u2 = comb2(ga##S##_2, gb##S##_2, kc##S##_2);              \
        const uint2 u3 = comb2(ga##S##_3, gb##S##_3, kc##S##_3);              \
        t4_##S = comb2(comb2(u0, u1, kd##S##_0), comb2(u2, u3, kd##S##_1), ke##S); \
        FOLD                                                                  \
    }

__global__ __launch_bounds__(TPB) void logic_conv_kernel(
    const float* __restrict__ x,
    const int*   __restrict__ h_idx,
    const int*   __restrict__ w_idx,
    const int*   __restrict__ c_idx,
    const float* __restrict__ w0, const float* __restrict__ w1,
    const float* __restrict__ w2, const float* __restrict__ w3,
    const float* __restrict__ w4, const float* __restrict__ w5,
    float* __restrict__ out)
{
    __shared__ unsigned int xsh[2 * DWCOPY];   // 12,672 B
    __shared__ uint4 coefb[63];                // pre-broadcast half2 coefs
    __shared__ int2  bases[32];

    const int tid = threadIdx.x;
    const int blk = blockIdx.x;
    const int k   = blk & 31;                  // fastest: L2 x-strip reuse
    const int t   = blk >> 5;
    const int st  = t % NSTRIP;
    const int b   = t / NSTRIP;
    const int oh0 = st * STRIP;

    // ---- stage rows [oh0, oh0+16) of x[b] as fp16, two shifted copies ----
    const float* xb = x + b * (Cc * Hh * Ww);
    #pragma unroll
    for (int it = 0; it < 4; ++it) {
        const int flat = it * TPB + tid;       // chunk of 4 floats, 0..767
        const int c    = flat >> 8;            // / 256  (16 rows * 16 chunks)
        const int rem  = flat & 255;
        const int r    = rem >> 4;
        const int w4i  = rem & 15;
        const int w0c  = w4i << 2;
        const float* src = xb + c * (Hh * Ww) + (oh0 + r) * Ww + w0c;
        const vf4u A = *reinterpret_cast<const vf4u*>(src);
        vf4u Bv;
        if (w4i < 15) Bv = *reinterpret_cast<const vf4u*>(src + 1);
        else          Bv = (vf4u){A.y, A.z, A.w, A.w};   // tail pad, never read
        const int di = c * DWC + r * DWROW + (w0c >> 1);
        xsh[di]              = pkh(A.x, A.y);
        xsh[di + 1]          = pkh(A.z, A.w);
        xsh[DWCOPY + di]     = pkh(Bv.x, Bv.y);
        xsh[DWCOPY + di + 1] = pkh(Bv.z, Bv.w);
    }

    // ---- gather bases (dword index, copy by col parity) ----
    if (tid < 32) {
        const int i0 = (0 * Kk + k) * Ss + tid;
        const int i1 = (1 * Kk + k) * Ss + tid;
        const int wA = w_idx[i0], sA = wA & 1;
        const int wB = w_idx[i1], sB = wB & 1;
        bases[tid] = make_int2(
            sA * DWCOPY + c_idx[i0] * DWC + h_idx[i0] * DWROW + ((wA - sA) >> 1),
            sB * DWCOPY + c_idx[i1] * DWC + h_idx[i1] * DWROW + ((wB - sB) >> 1));
    }

    // ---- per-node coefficients: softmax/LUT folded, packed as bcast half2 ----
    if (tid >= 64 && tid < 127) {
        const int tt = tid - 64;
        const float* wp; int n;
        if      (tt < 32) { wp = w0; n = tt;      }
        else if (tt < 48) { wp = w1; n = tt - 32; }
        else if (tt < 56) { wp = w2; n = tt - 48; }
        else if (tt < 60) { wp = w3; n = tt - 56; }
        else if (tt < 62) { wp = w4; n = tt - 60; }
        else              { wp = w5; n = 0;       }
        const float* lg = wp + (n * Kk + k) * 16;
        float l[16];
        float m = lg[0];
        #pragma unroll
        for (int q = 0; q < 16; ++q) { l[q] = lg[q]; m = fmaxf(m, l[q]); }
        float e[16], s = 0.f;
        #pragma unroll
        for (int q = 0; q < 16; ++q) { e[q] = __expf(l[q] - m); s += e[q]; }
        const float inv = 1.f / s;
        float c0 = 0.f, c1 = 0.f, c2 = 0.f, c3 = 0.f;
        #pragma unroll
        for (int op = 0; op < 16; ++op) {
            if (op & 1) c0 += e[op];
            if (op & 2) c1 += e[op];
            if (op & 4) c2 += e[op];
            if (op & 8) c3 += e[op];
        }
        c0 *= inv; c1 *= inv; c2 *= inv; c3 *= inv;
        const float dA = c2 - c0, dB = c1 - c0, dAB = c0 - c1 - c2 + c3;
        coefb[tt] = make_uint4(pkh(c0, c0), pkh(dA, dA), pkh(dB, dB), pkh(dAB, dAB));
    }

    __syncthreads();

    // ---- hoisted wave-uniform leaf bases -> SGPRs ----
    RFL(0,0, 0) RFL(0,1, 1) RFL(0,2, 2) RFL(0,3, 3)
    RFL(1,0, 4) RFL(1,1, 5) RFL(1,2, 6) RFL(1,3, 7)
    RFL(2,0, 8) RFL(2,1, 9) RFL(2,2,10) RFL(2,3,11)
    RFL(3,0,12) RFL(3,1,13) RFL(3,2,14) RFL(3,3,15)
    RFL(4,0,16) RFL(4,1,17) RFL(4,2,18) RFL(4,3,19)
    RFL(5,0,20) RFL(5,1,21) RFL(5,2,22) RFL(5,3,23)
    RFL(6,0,24) RFL(6,1,25) RFL(6,2,26) RFL(6,3,27)
    RFL(7,0,28) RFL(7,1,29) RFL(7,2,30) RFL(7,3,31)

    // ---- main: one 4-px group per thread, fp16 pipelined 8-stage tree ----
    if (tid < NGRP) {
        const int oh   = tid % STRIP;          // consecutive lanes -> rows
        const int owg  = tid / STRIP;          // 0..14
        const int loff = oh * DWROW + (owg << 1);

        uint2 t8a, t8b, t16a, t8a2, t8b2, t16b, y;

        PREG(0)
        COEF(0) PREG(1) SB;
        FMAS(0, )
        COEF(1) PREG(2) SB;
        FMAS(1, t8a = comb2(t4_0, t4_1, coefb[56]);)
        COEF(2) PREG(3) SB;
        FMAS(2, )
        COEF(3) PREG(4) SB;
        FMAS(3, t8b = comb2(t4_2, t4_3, coefb[57]);
                t16a = comb2(t8a, t8b, coefb[60]);)
        COEF(4) PREG(5) SB;
        FMAS(4, )
        COEF(5) PREG(6) SB;
        FMAS(5, t8a2 = comb2(t4_4, t4_5, coefb[58]);)
        COEF(6) PREG(7) SB;
        FMAS(6, )
        COEF(7) SB;
        FMAS(7, t8b2 = comb2(t4_6, t4_7, coefb[59]);
                t16b = comb2(t8a2, t8b2, coefb[61]);
                y = comb2(t16a, t16b, coefb[62]);)
        SB;

        // fp16 -> f32 only at the output store
        const float2 ylo = __half22float2(bc(y.x));
        const float2 yhi = __half22float2(bc(y.y));
        float* const outp = out + (b * Kk + k) * Pp + (oh0 + oh) * OWw + (owg << 2);
        *reinterpret_cast<vf4*>(outp) = (vf4){ylo.x, ylo.y, yhi.x, yhi.y};
    }
}

extern "C" void kernel_launch(void* const* d_in, const int* in_sizes, int n_in,
                              void* d_out, int out_size, void* d_ws, size_t ws_size,
                              hipStream_t stream) {
    const float* x     = (const float*)d_in[0];
    const int*   h_idx = (const int*)d_in[1];
    const int*   w_idx = (const int*)d_in[2];
    const int*   c_idx = (const int*)d_in[3];
    const float* w0    = (const float*)d_in[4];
    const float* w1    = (const float*)d_in[5];
    const float* w2    = (const float*)d_in[6];
    const float* w3    = (const float*)d_in[7];
    const float* w4    = (const float*)d_in[8];
    const float* w5    = (const float*)d_in[9];
    float* out = (float*)d_out;

    dim3 grid(Bb * NSTRIP * Kk);   // 2560 blocks: (b, strip, k) k fastest
    dim3 block(TPB);
    hipLaunchKernelGGL(logic_conv_kernel, grid, block, 0, stream,
                       x, h_idx, w_idx, c_idx, w0, w1, w2, w3, w4, w5, out);
}

// Round 15
// 21.878 us; speedup vs baseline: 1.1074x; 1.1074x over previous
//
#include <hip/hip_runtime.h>
#include <hip/hip_fp16.h>
#include <math.h>

// Problem constants (match reference)
#define Bb   16
#define Cc   3
#define Hh   64
#define Ww   64
#define Kk   32
#define Ss   32
#define OHh  60
#define OWw  60
#define Pp   3600
#define ROWS 34            // staged rows per block: 30 output rows + R-1
#define OHSUB 30
#define TPB  256

// fp16 LDS layout (dword units): row = 33 dwords. Bank stride/row = 1 ->
// oh-major lanes conflict-free. Two copies (shift 0/1 col): every 4-px
// gather is one ds_read2_b32, dwords are direct __half2 operands.
#define DWROW  33
#define DWC    (ROWS * DWROW)   // 1122 dwords per channel
#define DWCOPY (Cc * DWC)       // 3366 dwords per copy

typedef float vf4 __attribute__((ext_vector_type(4)));
typedef float vf4u __attribute__((ext_vector_type(4), aligned(4)));

#define SB __builtin_amdgcn_sched_barrier(0)

static __device__ __forceinline__ unsigned int pkh(float lo, float hi) {
    __half2 h = __floats2half2_rn(lo, hi);
    return *reinterpret_cast<unsigned int*>(&h);
}
static __device__ __forceinline__ __half2 bc(unsigned int u) {
    return *reinterpret_cast<__half2*>(&u);
}
static __device__ __forceinline__ unsigned int bits(__half2 h) {
    return *reinterpret_cast<unsigned int*>(&h);
}

// fp16 combine on 4 px (2 half2): y = c0 + a*dA + b*dB + a*b*dAB
// coef uint4 = pre-broadcast half2: {c0,c0},{dA,dA},{dB,dB},{dAB,dAB}
static __device__ __forceinline__ uint2 comb2(uint2 a, uint2 b, uint4 c) {
    const __half2 cc0 = bc(c.x), ccA = bc(c.y), ccB = bc(c.z), ccAB = bc(c.w);
    const __half2 tx = __hfma2(bc(b.x), ccAB, ccA);
    const __half2 ty = __hfma2(bc(b.y), ccAB, ccA);
    const __half2 ux = __hfma2(bc(b.x), ccB, cc0);
    const __half2 uy = __hfma2(bc(b.y), ccB, cc0);
    uint2 r;
    r.x = bits(__hfma2(bc(a.x), tx, ux));
    r.y = bits(__hfma2(bc(a.y), ty, uy));
    return r;
}

// raw gather: two adjacent dwords -> one ds_read2_b32 (base is SGPR-resident)
#define GR(sb, lofs, dst) { dst.x = xsh[(sb) + (lofs)]; dst.y = xsh[(sb) + (lofs) + 1]; }

// prologue: wave-uniform leaf bases -> SGPRs (readfirstlane)
#define RFL(S, J, IDX)                                                        \
    const int sbx##S##_##J = __builtin_amdgcn_readfirstlane(bases[(IDX)].x);  \
    const int sby##S##_##J = __builtin_amdgcn_readfirstlane(bases[(IDX)].y);

// read stage-S coefficients (7 uniform b128, LDS broadcast) -- shared by BOTH groups
#define COEF(S)                                                               \
    const uint4 kc##S##_0 = coefb[4*(S)],    kc##S##_1 = coefb[4*(S)+1];      \
    const uint4 kc##S##_2 = coefb[4*(S)+2],  kc##S##_3 = coefb[4*(S)+3];      \
    const uint4 kd##S##_0 = coefb[32+2*(S)], kd##S##_1 = coefb[33+2*(S)];     \
    const uint4 ke##S = coefb[48+(S)];

// One SUB4 stage for BOTH row-groups (rows oh and oh+15): 7 coef + 16 gather
// DS ops, then fp16 FMA trees for both. SB at end bounds live ranges.
#define STAGE(S, FOLD)                                                        \
    uint2 t4A_##S, t4B_##S;                                                   \
    {                                                                         \
        COEF(S)                                                               \
        uint2 gaA0, gbA0, gaA1, gbA1, gaA2, gbA2, gaA3, gbA3;                 \
        uint2 gaB0, gbB0, gaB1, gbB1, gaB2, gbB2, gaB3, gbB3;                 \
        GR(sbx##S##_0, loffA, gaA0); GR(sby##S##_0, loffA, gbA0);             \
        GR(sbx##S##_1, loffA, gaA1); GR(sby##S##_1, loffA, gbA1);             \
        GR(sbx##S##_2, loffA, gaA2); GR(sby##S##_2, loffA, gbA2);             \
        GR(sbx##S##_3, loffA, gaA3); GR(sby##S##_3, loffA, gbA3);             \
        GR(sbx##S##_0, loffB, gaB0); GR(sby##S##_0, loffB, gbB0);             \
        GR(sbx##S##_1, loffB, gaB1); GR(sby##S##_1, loffB, gbB1);             \
        GR(sbx##S##_2, loffB, gaB2); GR(sby##S##_2, loffB, gbB2);             \
        GR(sbx##S##_3, loffB, gaB3); GR(sby##S##_3, loffB, gbB3);             \
        {                                                                     \
            const uint2 u0 = comb2(gaA0, gbA0, kc##S##_0);                    \
            const uint2 u1 = comb2(gaA1, gbA1, kc##S##_1);                    \
            const uint2 u2 = comb2(gaA2, gbA2, kc##S##_2);                    \
            const uint2 u3 = comb2(gaA3, gbA3, kc##S##_3);                    \
            t4A_##S = comb2(comb2(u0, u1, kd##S##_0), comb2(u2, u3, kd##S##_1), ke##S); \
        }                                                                     \
        {                                                                     \
            const uint2 u0 = comb2(gaB0, gbB0, kc##S##_0);                    \
            const uint2 u1 = comb2(gaB1, gbB1, kc##S##_1);                    \
            const uint2 u2 = comb2(gaB2, gbB2, kc##S##_2);                    \
            const uint2 u3 = comb2(gaB3, gbB3, kc##S##_3);                    \
            t4B_##S = comb2(comb2(u0, u1, kd##S##_0), comb2(u2, u3, kd##S##_1), ke##S); \
        }                                                                     \
        FOLD                                                                  \
        SB;                                                                   \
    }

__global__ __launch_bounds__(TPB) void logic_conv_kernel(
    const float* __restrict__ x,
    const int*   __restrict__ h_idx,
    const int*   __restrict__ w_idx,
    const int*   __restrict__ c_idx,
    const float* __restrict__ w0, const float* __restrict__ w1,
    const float* __restrict__ w2, const float* __restrict__ w3,
    const float* __restrict__ w4, const float* __restrict__ w5,
    float* __restrict__ out)
{
    __shared__ unsigned int xsh[2 * DWCOPY];   // 26,928 B
    __shared__ uint4 coefb[63];                // pre-broadcast half2 coefs
    __shared__ int2  bases[32];

    const int tid  = threadIdx.x;
    const int blk  = blockIdx.x;
    const int b    = blk >> 6;
    const int k    = (blk >> 1) & 31;
    const int half = blk & 1;
    const int oh0  = half * OHSUB;

    // ---- stage rows [oh0, oh0+34) of x[b] as fp16, two shifted copies ----
    const float* xb = x + b * (Cc * Hh * Ww);
    #pragma unroll
    for (int it = 0; it < 7; ++it) {
        const int flat = it * TPB + tid;
        if (flat < Cc * ROWS * 16) {
            const int c   = flat / (ROWS * 16);
            const int rem = flat - c * (ROWS * 16);
            const int r   = rem >> 4;
            const int w4i = rem & 15;
            const int w0c = w4i << 2;
            const float* src = xb + c * (Hh * Ww) + (oh0 + r) * Ww + w0c;
            const vf4u A = *reinterpret_cast<const vf4u*>(src);
            vf4u Bv;
            if (w4i < 15) Bv = *reinterpret_cast<const vf4u*>(src + 1);
            else          Bv = (vf4u){A.y, A.z, A.w, A.w};
            const int di = c * DWC + r * DWROW + (w0c >> 1);
            xsh[di]              = pkh(A.x, A.y);
            xsh[di + 1]          = pkh(A.z, A.w);
            xsh[DWCOPY + di]     = pkh(Bv.x, Bv.y);
            xsh[DWCOPY + di + 1] = pkh(Bv.z, Bv.w);
        }
    }

    // ---- gather bases (dword index, copy by col parity) ----
    if (tid < 32) {
        const int i0 = (0 * Kk + k) * Ss + tid;
        const int i1 = (1 * Kk + k) * Ss + tid;
        const int wA = w_idx[i0], sA = wA & 1;
        const int wB = w_idx[i1], sB = wB & 1;
        bases[tid] = make_int2(
            sA * DWCOPY + c_idx[i0] * DWC + h_idx[i0] * DWROW + ((wA - sA) >> 1),
            sB * DWCOPY + c_idx[i1] * DWC + h_idx[i1] * DWROW + ((wB - sB) >> 1));
    }

    // ---- per-node coefficients: softmax/LUT folded, packed as bcast half2 ----
    if (tid >= 64 && tid < 127) {
        const int t = tid - 64;
        const float* wp; int n;
        if      (t < 32) { wp = w0; n = t;      }
        else if (t < 48) { wp = w1; n = t - 32; }
        else if (t < 56) { wp = w2; n = t - 48; }
        else if (t < 60) { wp = w3; n = t - 56; }
        else if (t < 62) { wp = w4; n = t - 60; }
        else             { wp = w5; n = 0;      }
        const float* lg = wp + (n * Kk + k) * 16;
        float l[16];
        float m = lg[0];
        #pragma unroll
        for (int q = 0; q < 16; ++q) { l[q] = lg[q]; m = fmaxf(m, l[q]); }
        float e[16], s = 0.f;
        #pragma unroll
        for (int q = 0; q < 16; ++q) { e[q] = __expf(l[q] - m); s += e[q]; }
        const float inv = 1.f / s;
        float c0 = 0.f, c1 = 0.f, c2 = 0.f, c3 = 0.f;
        #pragma unroll
        for (int op = 0; op < 16; ++op) {
            if (op & 1) c0 += e[op];
            if (op & 2) c1 += e[op];
            if (op & 4) c2 += e[op];
            if (op & 8) c3 += e[op];
        }
        c0 *= inv; c1 *= inv; c2 *= inv; c3 *= inv;
        const float dA = c2 - c0, dB = c1 - c0, dAB = c0 - c1 - c2 + c3;
        coefb[t] = make_uint4(pkh(c0, c0), pkh(dA, dA), pkh(dB, dB), pkh(dAB, dAB));
    }

    __syncthreads();

    // ---- hoisted wave-uniform leaf bases -> SGPRs ----
    RFL(0,0, 0) RFL(0,1, 1) RFL(0,2, 2) RFL(0,3, 3)
    RFL(1,0, 4) RFL(1,1, 5) RFL(1,2, 6) RFL(1,3, 7)
    RFL(2,0, 8) RFL(2,1, 9) RFL(2,2,10) RFL(2,3,11)
    RFL(3,0,12) RFL(3,1,13) RFL(3,2,14) RFL(3,3,15)
    RFL(4,0,16) RFL(4,1,17) RFL(4,2,18) RFL(4,3,19)
    RFL(5,0,20) RFL(5,1,21) RFL(5,2,22) RFL(5,3,23)
    RFL(6,0,24) RFL(6,1,25) RFL(6,2,26) RFL(6,3,27)
    RFL(7,0,28) RFL(7,1,29) RFL(7,2,30) RFL(7,3,31)

    // ---- main: TWO 4-px groups per thread (rows oh and oh+15, same owg),
    //      sharing all coef reads; single pass, 225/256 lanes active ----
    if (tid < 225) {
        const int oh    = tid % 15;                // consecutive lanes -> rows
        const int owg   = tid / 15;                // 0..14
        const int loffA = oh * DWROW + (owg << 1); // row oh
        const int loffB = loffA + 15 * DWROW;      // row oh+15

        uint2 t8aA, t8bA, t16aA, t8a2A, t8b2A, t16bA, yA;
        uint2 t8aB, t8bB, t16aB, t8a2B, t8b2B, t16bB, yB;

        STAGE(0, )
        STAGE(1, t8aA = comb2(t4A_0, t4A_1, coefb[56]);
                 t8aB = comb2(t4B_0, t4B_1, coefb[56]);)
        STAGE(2, )
        STAGE(3, t8bA = comb2(t4A_2, t4A_3, coefb[57]);
                 t8bB = comb2(t4B_2, t4B_3, coefb[57]);
                 t16aA = comb2(t8aA, t8bA, coefb[60]);
                 t16aB = comb2(t8aB, t8bB, coefb[60]);)
        STAGE(4, )
        STAGE(5, t8a2A = comb2(t4A_4, t4A_5, coefb[58]);
                 t8a2B = comb2(t4B_4, t4B_5, coefb[58]);)
        STAGE(6, )
        STAGE(7, t8b2A = comb2(t4A_6, t4A_7, coefb[59]);
                 t8b2B = comb2(t4B_6, t4B_7, coefb[59]);
                 t16bA = comb2(t8a2A, t8b2A, coefb[61]);
                 t16bB = comb2(t8a2B, t8b2B, coefb[61]);
                 yA = comb2(t16aA, t16bA, coefb[62]);
                 yB = comb2(t16aB, t16bB, coefb[62]);)

        // fp16 -> f32 only at the output store
        const float2 yloA = __half22float2(bc(yA.x));
        const float2 yhiA = __half22float2(bc(yA.y));
        const float2 yloB = __half22float2(bc(yB.x));
        const float2 yhiB = __half22float2(bc(yB.y));
        float* const outp = out + (b * Kk + k) * Pp + (oh0 + oh) * OWw + (owg << 2);
        *reinterpret_cast<vf4*>(outp)            = (vf4){yloA.x, yloA.y, yhiA.x, yhiA.y};
        *reinterpret_cast<vf4*>(outp + 15 * OWw) = (vf4){yloB.x, yloB.y, yhiB.x, yhiB.y};
    }
}

extern "C" void kernel_launch(void* const* d_in, const int* in_sizes, int n_in,
                              void* d_out, int out_size, void* d_ws, size_t ws_size,
                              hipStream_t stream) {
    const float* x     = (const float*)d_in[0];
    const int*   h_idx = (const int*)d_in[1];
    const int*   w_idx = (const int*)d_in[2];
    const int*   c_idx = (const int*)d_in[3];
    const float* w0    = (const float*)d_in[4];
    const float* w1    = (const float*)d_in[5];
    const float* w2    = (const float*)d_in[6];
    const float* w3    = (const float*)d_in[7];
    const float* w4    = (const float*)d_in[8];
    const float* w5    = (const float*)d_in[9];
    float* out = (float*)d_out;

    dim3 grid(Bb * Kk * 2);   // 1024 blocks: (b, k, row-half)
    dim3 block(TPB);
    hipLaunchKernelGGL(logic_conv_kernel, grid, block, 0, stream,
                       x, h_idx, w_idx, c_idx, w0, w1, w2, w3, w4, w5, out);
}

// Round 16
// 21.080 us; speedup vs baseline: 1.1493x; 1.0379x over previous
//
#include <hip/hip_runtime.h>
#include <hip/hip_fp16.h>
#include <math.h>

// Problem constants (match reference)
#define Bb   16
#define Cc   3
#define Hh   64
#define Ww   64
#define Kk   32
#define Ss   32
#define OHh  60
#define OWw  60
#define Pp   3600
#define ROWS 34            // staged rows per block: 30 output rows + R-1
#define OHSUB 30
#define NTILE 450          // 15 row-pairs * 30 col-pairs
#define TPB  256

// fp16 LDS layout (dword units): row = 33 dwords. Two copies (shift 0/1 col).
// 2x2-tile gather: one ds_read2_b32, offsets {0, +33} (rows r, r+1; one dword
// = 2 cols each). Lane bank = 2*oh2 + ow2 -> ~2-way across the wave (free).
#define DWROW  33
#define DWC    (ROWS * DWROW)   // 1122 dwords per channel
#define DWCOPY (Cc * DWC)       // 3366 dwords per copy

typedef float vf4 __attribute__((ext_vector_type(4)));
typedef float vf4u __attribute__((ext_vector_type(4), aligned(4)));

#define SB __builtin_amdgcn_sched_barrier(0)

static __device__ __forceinline__ unsigned int pkh(float lo, float hi) {
    __half2 h = __floats2half2_rn(lo, hi);
    return *reinterpret_cast<unsigned int*>(&h);
}
static __device__ __forceinline__ __half2 bc(unsigned int u) {
    return *reinterpret_cast<__half2*>(&u);
}
static __device__ __forceinline__ unsigned int bits(__half2 h) {
    return *reinterpret_cast<unsigned int*>(&h);
}

// fp16 combine on a 2x2 tile (x = top row half2, y = bottom row half2)
// coef uint4 = pre-broadcast half2: {c0,c0},{dA,dA},{dB,dB},{dAB,dAB}
static __device__ __forceinline__ uint2 comb2(uint2 a, uint2 b, uint4 c) {
    const __half2 cc0 = bc(c.x), ccA = bc(c.y), ccB = bc(c.z), ccAB = bc(c.w);
    const __half2 tx = __hfma2(bc(b.x), ccAB, ccA);
    const __half2 ty = __hfma2(bc(b.y), ccAB, ccA);
    const __half2 ux = __hfma2(bc(b.x), ccB, cc0);
    const __half2 uy = __hfma2(bc(b.y), ccB, cc0);
    uint2 r;
    r.x = bits(__hfma2(bc(a.x), tx, ux));
    r.y = bits(__hfma2(bc(a.y), ty, uy));
    return r;
}

// 2x2-tile gather: rows r,r+1 (offset +DWROW) -> one ds_read2_b32
#define GR(sb, dst) { dst.x = xsh[(sb) + loff]; dst.y = xsh[(sb) + loff + DWROW]; }

// prologue: wave-uniform leaf bases -> SGPRs (readfirstlane)
#define RFL(S, J, IDX)                                                        \
    const int sbx##S##_##J = __builtin_amdgcn_readfirstlane(bases[(IDX)].x);  \
    const int sby##S##_##J = __builtin_amdgcn_readfirstlane(bases[(IDX)].y);

// issue stage-S gathers (8 ds_read2_b32)
#define PREG(S)                                                               \
    uint2 ga##S##_0, gb##S##_0, ga##S##_1, gb##S##_1;                         \
    uint2 ga##S##_2, gb##S##_2, ga##S##_3, gb##S##_3;                         \
    GR(sbx##S##_0, ga##S##_0); GR(sby##S##_0, gb##S##_0);                     \
    GR(sbx##S##_1, ga##S##_1); GR(sby##S##_1, gb##S##_1);                     \
    GR(sbx##S##_2, ga##S##_2); GR(sby##S##_2, gb##S##_2);                     \
    GR(sbx##S##_3, ga##S##_3); GR(sby##S##_3, gb##S##_3);

// read stage-S coefficients (7 uniform b128, LDS broadcast)
#define COEF(S)                                                               \
    const uint4 kc##S##_0 = coefb[4*(S)],    kc##S##_1 = coefb[4*(S)+1];      \
    const uint4 kc##S##_2 = coefb[4*(S)+2],  kc##S##_3 = coefb[4*(S)+3];      \
    const uint4 kd##S##_0 = coefb[32+2*(S)], kd##S##_1 = coefb[33+2*(S)];     \
    const uint4 ke##S = coefb[48+(S)];

// fp16 FMA tree for stage S
#define FMAS(S, FOLD)                                                         \
    uint2 t4_##S;                                                             \
    {                                                                         \
        const uint2 u0 = comb2(ga##S##_0, gb##S##_0, kc##S##_0);              \
        const uint2 u1 = comb2(ga##S##_1, gb##S##_1, kc##S##_1);              \
        const uint2 u2 = comb2(ga##S##_2, gb##S##_2, kc##S##_2);              \
        const uint2 u3 = comb2(ga##S##_3, gb##S##_3, kc##S##_3);              \
        t4_##S = comb2(comb2(u0, u1, kd##S##_0), comb2(u2, u3, kd##S##_1), ke##S); \
        FOLD                                                                  \
    }

__global__ __launch_bounds__(TPB) void logic_conv_kernel(
    const float* __restrict__ x,
    const int*   __restrict__ h_idx,
    const int*   __restrict__ w_idx,
    const int*   __restrict__ c_idx,
    const float* __restrict__ w0, const float* __restrict__ w1,
    const float* __restrict__ w2, const float* __restrict__ w3,
    const float* __restrict__ w4, const float* __restrict__ w5,
    float* __restrict__ out)
{
    __shared__ unsigned int xsh[2 * DWCOPY];   // 26,928 B
    __shared__ uint4 coefb[63];                // pre-broadcast half2 coefs
    __shared__ int2  bases[32];

    const int tid  = threadIdx.x;
    const int blk  = blockIdx.x;
    const int b    = blk >> 6;
    const int k    = (blk >> 1) & 31;
    const int half = blk & 1;
    const int oh0  = half * OHSUB;

    // ---- stage rows [oh0, oh0+34) of x[b] as fp16, two shifted copies ----
    const float* xb = x + b * (Cc * Hh * Ww);
    #pragma unroll
    for (int it = 0; it < 7; ++it) {
        const int flat = it * TPB + tid;
        if (flat < Cc * ROWS * 16) {
            const int c   = flat / (ROWS * 16);
            const int rem = flat - c * (ROWS * 16);
            const int r   = rem >> 4;
            const int w4i = rem & 15;
            const int w0c = w4i << 2;
            const float* src = xb + c * (Hh * Ww) + (oh0 + r) * Ww + w0c;
            const vf4u A = *reinterpret_cast<const vf4u*>(src);
            vf4u Bv;
            if (w4i < 15) Bv = *reinterpret_cast<const vf4u*>(src + 1);
            else          Bv = (vf4u){A.y, A.z, A.w, A.w};
            const int di = c * DWC + r * DWROW + (w0c >> 1);
            xsh[di]              = pkh(A.x, A.y);
            xsh[di + 1]          = pkh(A.z, A.w);
            xsh[DWCOPY + di]     = pkh(Bv.x, Bv.y);
            xsh[DWCOPY + di + 1] = pkh(Bv.z, Bv.w);
        }
    }

    // ---- gather bases (dword index, copy by col parity) ----
    if (tid < 32) {
        const int i0 = (0 * Kk + k) * Ss + tid;
        const int i1 = (1 * Kk + k) * Ss + tid;
        const int wA = w_idx[i0], sA = wA & 1;
        const int wB = w_idx[i1], sB = wB & 1;
        bases[tid] = make_int2(
            sA * DWCOPY + c_idx[i0] * DWC + h_idx[i0] * DWROW + ((wA - sA) >> 1),
            sB * DWCOPY + c_idx[i1] * DWC + h_idx[i1] * DWROW + ((wB - sB) >> 1));
    }

    // ---- per-node coefficients: softmax/LUT folded, packed as bcast half2 ----
    if (tid >= 64 && tid < 127) {
        const int t = tid - 64;
        const float* wp; int n;
        if      (t < 32) { wp = w0; n = t;      }
        else if (t < 48) { wp = w1; n = t - 32; }
        else if (t < 56) { wp = w2; n = t - 48; }
        else if (t < 60) { wp = w3; n = t - 56; }
        else if (t < 62) { wp = w4; n = t - 60; }
        else             { wp = w5; n = 0;      }
        const float* lg = wp + (n * Kk + k) * 16;
        float l[16];
        float m = lg[0];
        #pragma unroll
        for (int q = 0; q < 16; ++q) { l[q] = lg[q]; m = fmaxf(m, l[q]); }
        float e[16], s = 0.f;
        #pragma unroll
        for (int q = 0; q < 16; ++q) { e[q] = __expf(l[q] - m); s += e[q]; }
        const float inv = 1.f / s;
        float c0 = 0.f, c1 = 0.f, c2 = 0.f, c3 = 0.f;
        #pragma unroll
        for (int op = 0; op < 16; ++op) {
            if (op & 1) c0 += e[op];
            if (op & 2) c1 += e[op];
            if (op & 4) c2 += e[op];
            if (op & 8) c3 += e[op];
        }
        c0 *= inv; c1 *= inv; c2 *= inv; c3 *= inv;
        const float dA = c2 - c0, dB = c1 - c0, dAB = c0 - c1 - c2 + c3;
        coefb[t] = make_uint4(pkh(c0, c0), pkh(dA, dA), pkh(dB, dB), pkh(dAB, dAB));
    }

    __syncthreads();

    // ---- hoisted wave-uniform leaf bases -> SGPRs ----
    RFL(0,0, 0) RFL(0,1, 1) RFL(0,2, 2) RFL(0,3, 3)
    RFL(1,0, 4) RFL(1,1, 5) RFL(1,2, 6) RFL(1,3, 7)
    RFL(2,0, 8) RFL(2,1, 9) RFL(2,2,10) RFL(2,3,11)
    RFL(3,0,12) RFL(3,1,13) RFL(3,2,14) RFL(3,3,15)
    RFL(4,0,16) RFL(4,1,17) RFL(4,2,18) RFL(4,3,19)
    RFL(5,0,20) RFL(5,1,21) RFL(5,2,22) RFL(5,3,23)
    RFL(6,0,24) RFL(6,1,25) RFL(6,2,26) RFL(6,3,27)
    RFL(7,0,28) RFL(7,1,29) RFL(7,2,30) RFL(7,3,31)

    // ---- main: one 2x2 tile per thread-iteration ----
    float* const outb = out + (b * Kk + k) * Pp + oh0 * OWw;
    #pragma unroll 1
    for (int it = 0; it < 2; ++it) {
        const int g = it * TPB + tid;
        if (g < NTILE) {
            const int oh2 = g % 15;            // row-pair index: rows 2*oh2, +1
            const int ow2 = g / 15;            // col-pair index: dword col ow2
            const int loff = (oh2 * 2) * DWROW + ow2;   // bank = 2*oh2+ow2: ~2-way

            uint2 t8a, t8b, t16a, t8a2, t8b2, t16b, y;

            PREG(0)
            COEF(0) PREG(1) SB;
            FMAS(0, )
            COEF(1) PREG(2) SB;
            FMAS(1, t8a = comb2(t4_0, t4_1, coefb[56]);)
            COEF(2) PREG(3) SB;
            FMAS(2, )
            COEF(3) PREG(4) SB;
            FMAS(3, t8b = comb2(t4_2, t4_3, coefb[57]);
                    t16a = comb2(t8a, t8b, coefb[60]);)
            COEF(4) PREG(5) SB;
            FMAS(4, )
            COEF(5) PREG(6) SB;
            FMAS(5, t8a2 = comb2(t4_4, t4_5, coefb[58]);)
            COEF(6) PREG(7) SB;
            FMAS(6, )
            COEF(7) SB;
            FMAS(7, t8b2 = comb2(t4_6, t4_7, coefb[59]);
                    t16b = comb2(t8a2, t8b2, coefb[61]);
                    y = comb2(t16a, t16b, coefb[62]);)
            SB;

            // fp16 -> f32 at store: two float2 rows of the 2x2 tile
            const float2 ytop = __half22float2(bc(y.x));
            const float2 ybot = __half22float2(bc(y.y));
            float* const outp = outb + (oh2 * 2) * OWw + (ow2 * 2);
            *reinterpret_cast<float2*>(outp)       = ytop;
            *reinterpret_cast<float2*>(outp + OWw) = ybot;
        }
    }
}

extern "C" void kernel_launch(void* const* d_in, const int* in_sizes, int n_in,
                              void* d_out, int out_size, void* d_ws, size_t ws_size,
                              hipStream_t stream) {
    const float* x     = (const float*)d_in[0];
    const int*   h_idx = (const int*)d_in[1];
    const int*   w_idx = (const int*)d_in[2];
    const int*   c_idx = (const int*)d_in[3];
    const float* w0    = (const float*)d_in[4];
    const float* w1    = (const float*)d_in[5];
    const float* w2    = (const float*)d_in[6];
    const float* w3    = (const float*)d_in[7];
    const float* w4    = (const float*)d_in[8];
    const float* w5    = (const float*)d_in[9];
    float* out = (float*)d_out;

    dim3 grid(Bb * Kk * 2);   // 1024 blocks: (b, k, row-half)
    dim3 block(TPB);
    hipLaunchKernelGGL(logic_conv_kernel, grid, block, 0, stream,
                       x, h_idx, w_idx, c_idx, w0, w1, w2, w3, w4, w5, out);
}